// Round 1
// baseline (751.875 us; speedup 1.0000x reference)
//
#include <hip/hip_runtime.h>
#include <hip/hip_bf16.h>
#include <stdint.h>

typedef short short8 __attribute__((ext_vector_type(8)));
typedef float f32x4 __attribute__((ext_vector_type(4)));

#define NBATCH 8
#define TSEQ   4096
#define CDIM   1024
#define HDIM   128
#define QK_SCALE 0.08838834764831845f   // 1/sqrt(128)
#define LOG2E    1.4426950408889634f

// ---- helpers -------------------------------------------------------------
__device__ __forceinline__ uint32_t cvt_pk_bf16(float lo, float hi) {
  uint32_t r;
  asm("v_cvt_pk_bf16_f32 %0, %1, %2" : "=v"(r) : "v"(lo), "v"(hi));
  return r;
}

__device__ __forceinline__ short8 pack_bf16x8(float4 a, float4 b) {
  union { short8 v; uint32_t u[4]; } r;
  r.u[0] = cvt_pk_bf16(a.x, a.y);
  r.u[1] = cvt_pk_bf16(a.z, a.w);
  r.u[2] = cvt_pk_bf16(b.x, b.y);
  r.u[3] = cvt_pk_bf16(b.z, b.w);
  return r.v;
}

__device__ __forceinline__ f32x4 mfma16(short8 a, short8 b, f32x4 c) {
  return __builtin_amdgcn_mfma_f32_16x16x32_bf16(a, b, c, 0, 0, 0);
}

// ---- prep: W -> bf16 cast + rope cos/sin table ----------------------------
__global__ void prep_kernel(const float* __restrict__ Wq,
                            const float* __restrict__ Wk,
                            const float* __restrict__ Wv,
                            __hip_bfloat16* __restrict__ W3,
                            float2* __restrict__ cs) {
  int idx = blockIdx.x * 256 + threadIdx.x;
  if (idx < 3 * HDIM * CDIM) {
    int which = idx >> 17;            // 131072 = 128*1024 per W
    int off   = idx & 131071;
    const float* s = (which == 0) ? Wq : (which == 1) ? Wk : Wv;
    W3[idx] = __float2bfloat16(s[off]);
  }
  if (idx < TSEQ * 64) {
    int t = idx >> 6, i = idx & 63;
    float freq = powf(10000.0f, -(float)i * (1.0f / 64.0f));
    float ang  = (float)t * freq;
    cs[idx] = make_float2(cosf(ang), sinf(ang));
  }
}

// ---- projection: q/k/v = x @ W^T, rope(q,k), q *= scale*log2e -------------
// grid (3, 128): blockIdx.x = which W (0=q,1=k,2=v), blockIdx.y = 256-row tile
// 8 waves, each wave: 32 t-rows x 128 h, MFMA 16x16x32 bf16.
// A-frag layout assumed: A[row=lane&15][k=(lane>>4)*8+j]; B[k][col=lane&15];
// D: col=lane&15, row=(lane>>4)*4+reg (m89-verified).
__global__ __launch_bounds__(512) void proj_kernel(
    const float* __restrict__ x,
    const __hip_bfloat16* __restrict__ W3,
    const float2* __restrict__ cs,
    __hip_bfloat16* __restrict__ qbuf,
    __hip_bfloat16* __restrict__ kbuf,
    __hip_bfloat16* __restrict__ vt) {
  const int lane = threadIdx.x & 63;
  const int wid  = threadIdx.x >> 6;
  const int qt   = lane & 15;
  const int g    = lane >> 4;
  const int n    = blockIdx.x;          // 0=q 1=k 2=v
  const int row0 = blockIdx.y * 256;
  const int wrow = row0 + wid * 32;

  const __hip_bfloat16* Wn = W3 + (size_t)n * (HDIM * CDIM);
  f32x4 zero = {0.f, 0.f, 0.f, 0.f};
  f32x4 acc[2][8];
#pragma unroll
  for (int ti = 0; ti < 2; ++ti)
#pragma unroll
    for (int hi = 0; hi < 8; ++hi) acc[ti][hi] = zero;

  const float* xr0 = x + (size_t)(wrow + qt) * CDIM + g * 8;
  const float* xr1 = xr0 + (size_t)16 * CDIM;
  const __hip_bfloat16* wr = Wn + (size_t)qt * CDIM + g * 8;

  if (n < 2) {
    // D[t][h]: A = x tile (rows = t), B = W^T (cols = h)
    for (int c0 = 0; c0 < CDIM; c0 += 32) {
      short8 xa0 = pack_bf16x8(*(const float4*)(xr0 + c0), *(const float4*)(xr0 + c0 + 4));
      short8 xa1 = pack_bf16x8(*(const float4*)(xr1 + c0), *(const float4*)(xr1 + c0 + 4));
#pragma unroll
      for (int hi = 0; hi < 8; ++hi) {
        short8 wf = *(const short8*)(wr + (size_t)hi * 16 * CDIM + c0);
        acc[0][hi] = mfma16(xa0, wf, acc[0][hi]);
        acc[1][hi] = mfma16(xa1, wf, acc[1][hi]);
      }
    }
  } else {
    // v: D[h][t]: A = W (rows = h), B = x^T (cols = t)  -> direct v^T store
    for (int c0 = 0; c0 < CDIM; c0 += 32) {
      short8 xa0 = pack_bf16x8(*(const float4*)(xr0 + c0), *(const float4*)(xr0 + c0 + 4));
      short8 xa1 = pack_bf16x8(*(const float4*)(xr1 + c0), *(const float4*)(xr1 + c0 + 4));
#pragma unroll
      for (int hi = 0; hi < 8; ++hi) {
        short8 wf = *(const short8*)(wr + (size_t)hi * 16 * CDIM + c0);
        acc[0][hi] = mfma16(wf, xa0, acc[0][hi]);
        acc[1][hi] = mfma16(wf, xa1, acc[1][hi]);
      }
    }
  }

  if (n < 2) {
    __hip_bfloat16* dst = (n == 0) ? qbuf : kbuf;
    const float qmul = (n == 0) ? (QK_SCALE * LOG2E) : 1.0f;
    const float sgn  = (qt & 1) ? 1.0f : -1.0f;   // even h: a*c - b*s ; odd: a*s + b*c
#pragma unroll
    for (int ti = 0; ti < 2; ++ti) {
#pragma unroll
      for (int hi = 0; hi < 8; ++hi) {
        const int h = hi * 16 + qt;
        const int i = h >> 1;
#pragma unroll
        for (int r = 0; r < 4; ++r) {
          const int grow = wrow + ti * 16 + g * 4 + r;   // global row = b*T + t
          const int trow = grow & (TSEQ - 1);
          float v   = acc[ti][hi][r];
          float prt = __shfl_xor(v, 1);                  // partner h^1, same t
          float2 c_s = cs[trow * 64 + i];
          float o = (v * c_s.x + prt * c_s.y * sgn) * qmul;
          dst[(size_t)grow * HDIM + h] = __float2bfloat16(o);
        }
      }
    }
  } else {
#pragma unroll
    for (int ti = 0; ti < 2; ++ti) {
#pragma unroll
      for (int hi = 0; hi < 8; ++hi) {
#pragma unroll
        for (int r = 0; r < 4; ++r) {
          const int h    = hi * 16 + g * 4 + r;
          const int grow = wrow + ti * 16 + qt;
          const int bb   = grow >> 12;
          const int trow = grow & (TSEQ - 1);
          vt[(size_t)bb * (HDIM * TSEQ) + (size_t)h * TSEQ + trow] =
              __float2bfloat16(acc[ti][hi][r]);
        }
      }
    }
  }
}

// ---- flash attention: causal, online softmax in exp2 domain ---------------
// grid (64, 8): 4 waves/block, wave owns 16 q rows, KV tiles of 32.
// S^T = mfma(K, Q): lane owns ONE q (=lane&15); k = 16*kt + g*4 + reg.
// PV: out^T = mfma(V^T, P^T); P^T B-frag built via cvt_pk + 8 bpermute.
__global__ __launch_bounds__(256) void attn_kernel(
    const __hip_bfloat16* __restrict__ qbuf,
    const __hip_bfloat16* __restrict__ kbuf,
    const __hip_bfloat16* __restrict__ vt,
    float* __restrict__ out) {
  const int lane = threadIdx.x & 63;
  const int wid  = threadIdx.x >> 6;
  const int qt   = lane & 15;
  const int g    = lane >> 4;
  const int b    = blockIdx.y;
  const int q0w  = ((int)gridDim.x - 1 - (int)blockIdx.x) * 64 + wid * 16; // heavy blocks first
  const int q    = q0w + qt;

  const __hip_bfloat16* qrow = qbuf + (size_t)(b * TSEQ + q) * HDIM + g * 8;
  short8 qf[4];
#pragma unroll
  for (int s = 0; s < 4; ++s) qf[s] = *(const short8*)(qrow + s * 32);

  f32x4 zero = {0.f, 0.f, 0.f, 0.f};
  f32x4 acc[8];
#pragma unroll
  for (int d = 0; d < 8; ++d) acc[d] = zero;
  float m = -3.0e38f, lsum = 0.0f;

  const __hip_bfloat16* kbb = kbuf + (size_t)b * TSEQ * HDIM;
  const __hip_bfloat16* vbb = vt   + (size_t)b * HDIM * TSEQ;
  const int ntiles = (q0w + 47) >> 5;

  const int L0  = qt | ((g & 1) << 5);
  const int L1  = L0 + 16;
  const int sel = g >> 1;

  for (int tile = 0; tile < ntiles; ++tile) {
    const int kv0 = tile * 32;
    const __hip_bfloat16* kp = kbb + (size_t)(kv0 + qt) * HDIM + g * 8;
    f32x4 s0 = {0.f, 0.f, 0.f, 0.f}, s1 = {0.f, 0.f, 0.f, 0.f};
#pragma unroll
    for (int s = 0; s < 4; ++s) {
      short8 kf0 = *(const short8*)(kp + s * 32);
      short8 kf1 = *(const short8*)(kp + 16 * HDIM + s * 32);
      s0 = mfma16(kf0, qf[s], s0);   // S^T tile kt=0
      s1 = mfma16(kf1, qf[s], s1);   // S^T tile kt=1
    }
    if (kv0 + 31 > q0w) {            // causal mask (tile straddles diagonal)
#pragma unroll
      for (int r = 0; r < 4; ++r) {
        const int kk = kv0 + g * 4 + r;
        if (kk > q)      s0[r] = -1.0e30f;
        if (kk + 16 > q) s1[r] = -1.0e30f;
      }
    }
    float tmax = fmaxf(fmaxf(fmaxf(s0[0], s0[1]), fmaxf(s0[2], s0[3])),
                       fmaxf(fmaxf(s1[0], s1[1]), fmaxf(s1[2], s1[3])));
    tmax = fmaxf(tmax, __shfl_xor(tmax, 16));
    tmax = fmaxf(tmax, __shfl_xor(tmax, 32));
    if (__any(tmax > m + 8.0f)) {    // defer-max (T13): exact normalization either way
      const float mn = fmaxf(m, tmax);
      const float f  = exp2f(m - mn);
      lsum *= f;
#pragma unroll
      for (int d = 0; d < 8; ++d) {
        acc[d][0] *= f; acc[d][1] *= f; acc[d][2] *= f; acc[d][3] *= f;
      }
      m = mn;
    }
    float p0[4], p1[4];
#pragma unroll
    for (int r = 0; r < 4; ++r) {
      p0[r] = exp2f(s0[r] - m);      // log2e*scale folded into stored q
      p1[r] = exp2f(s1[r] - m);
      lsum += p0[r] + p1[r];
    }
    // pack P to bf16 pairs, then permute to B-fragment layout (k=(g*8+j) per lane)
    const uint32_t pk00 = cvt_pk_bf16(p0[0], p0[1]);
    const uint32_t pk01 = cvt_pk_bf16(p0[2], p0[3]);
    const uint32_t pk10 = cvt_pk_bf16(p1[0], p1[1]);
    const uint32_t pk11 = cvt_pk_bf16(p1[2], p1[3]);
    const int a00 = __shfl((int)pk00, L0), a10 = __shfl((int)pk10, L0);
    const int a01 = __shfl((int)pk01, L0), a11 = __shfl((int)pk11, L0);
    const int a02 = __shfl((int)pk00, L1), a12 = __shfl((int)pk10, L1);
    const int a03 = __shfl((int)pk01, L1), a13 = __shfl((int)pk11, L1);
    union { short8 v; uint32_t u[4]; } pb;
    pb.u[0] = (uint32_t)(sel ? a10 : a00);
    pb.u[1] = (uint32_t)(sel ? a11 : a01);
    pb.u[2] = (uint32_t)(sel ? a12 : a02);
    pb.u[3] = (uint32_t)(sel ? a13 : a03);
    // PV: acc[dt] = out^T[d=dt*16+g*4+r][q]
    const __hip_bfloat16* vp = vbb + (size_t)qt * TSEQ + kv0 + g * 8;
#pragma unroll
    for (int d = 0; d < 8; ++d) {
      short8 vf = *(const short8*)(vp + (size_t)(d * 16) * TSEQ);
      acc[d] = mfma16(vf, pb.v, acc[d]);
    }
  }
  lsum += __shfl_xor(lsum, 16);
  lsum += __shfl_xor(lsum, 32);
  const float inv = 1.0f / lsum;
  float* orow = out + (size_t)(b * TSEQ + q) * HDIM;
#pragma unroll
  for (int d = 0; d < 8; ++d)
#pragma unroll
    for (int r = 0; r < 4; ++r)
      orow[d * 16 + g * 4 + r] = acc[d][r] * inv;
}

// ---- launch ----------------------------------------------------------------
extern "C" void kernel_launch(void* const* d_in, const int* in_sizes, int n_in,
                              void* d_out, int out_size, void* d_ws, size_t ws_size,
                              hipStream_t stream) {
  (void)in_sizes; (void)n_in; (void)out_size; (void)ws_size;
  const float* x  = (const float*)d_in[0];
  const float* Wq = (const float*)d_in[1];
  const float* Wk = (const float*)d_in[2];
  const float* Wv = (const float*)d_in[3];
  float* out = (float*)d_out;

  // ws layout (28 MiB total):
  //   [ 0, 2M)  float2 cos/sin [4096][64]
  //   [ 2M, ~)  bf16 W3 [3][128][1024]           (768 KiB)
  //   [ 4M,12M) bf16 q (roped, *scale*log2e)     [8*4096][128]
  //   [12M,20M) bf16 k (roped)                   [8*4096][128]
  //   [20M,28M) bf16 v^T                          [8][128][4096]
  char* ws = (char*)d_ws;
  float2*         cs   = (float2*)(ws);
  __hip_bfloat16* W3   = (__hip_bfloat16*)(ws + (2u  << 20));
  __hip_bfloat16* qbuf = (__hip_bfloat16*)(ws + (4u  << 20));
  __hip_bfloat16* kbuf = (__hip_bfloat16*)(ws + (12u << 20));
  __hip_bfloat16* vt   = (__hip_bfloat16*)(ws + (20u << 20));

  hipLaunchKernelGGL(prep_kernel, dim3(1536), dim3(256), 0, stream, Wq, Wk, Wv, W3, cs);
  hipLaunchKernelGGL(proj_kernel, dim3(3, 128), dim3(512), 0, stream, x, W3, cs, qbuf, kbuf, vt);
  hipLaunchKernelGGL(attn_kernel, dim3(64, 8), dim3(256), 0, stream, qbuf, kbuf, vt, out);
}

// Round 2
// 505.506 us; speedup vs baseline: 1.4874x; 1.4874x over previous
//
#include <hip/hip_runtime.h>
#include <hip/hip_bf16.h>
#include <stdint.h>

typedef short short8 __attribute__((ext_vector_type(8)));
typedef float f32x4 __attribute__((ext_vector_type(4)));

#define NBATCH 8
#define TSEQ   4096
#define CDIM   1024
#define HDIM   128
#define QK_SCALE 0.08838834764831845f   // 1/sqrt(128)
#define LOG2E    1.4426950408889634f

// ---- helpers -------------------------------------------------------------
__device__ __forceinline__ uint32_t cvt_pk_bf16(float lo, float hi) {
  uint32_t r;
  asm("v_cvt_pk_bf16_f32 %0, %1, %2" : "=v"(r) : "v"(lo), "v"(hi));
  return r;
}

__device__ __forceinline__ short8 pack_bf16x8(float4 a, float4 b) {
  union { short8 v; uint32_t u[4]; } r;
  r.u[0] = cvt_pk_bf16(a.x, a.y);
  r.u[1] = cvt_pk_bf16(a.z, a.w);
  r.u[2] = cvt_pk_bf16(b.x, b.y);
  r.u[3] = cvt_pk_bf16(b.z, b.w);
  return r.v;
}

__device__ __forceinline__ f32x4 mfma16(short8 a, short8 b, f32x4 c) {
  return __builtin_amdgcn_mfma_f32_16x16x32_bf16(a, b, c, 0, 0, 0);
}

// ---- prep: W -> bf16 cast + rope cos/sin table ----------------------------
__global__ void prep_kernel(const float* __restrict__ Wq,
                            const float* __restrict__ Wk,
                            const float* __restrict__ Wv,
                            __hip_bfloat16* __restrict__ W3,
                            float2* __restrict__ cs) {
  int idx = blockIdx.x * 256 + threadIdx.x;
  if (idx < 3 * HDIM * CDIM) {
    int which = idx >> 17;
    int off   = idx & 131071;
    const float* s = (which == 0) ? Wq : (which == 1) ? Wk : Wv;
    W3[idx] = __float2bfloat16(s[off]);
  }
  if (idx < TSEQ * 64) {
    int t = idx >> 6, i = idx & 63;
    float freq = powf(10000.0f, -(float)i * (1.0f / 64.0f));
    float ang  = (float)t * freq;
    cs[idx] = make_float2(cosf(ang), sinf(ang));
  }
}

// ---- projection: q/k/v fused (x read once), rope(q,k), q *= scale*log2e ---
// grid (256): blockIdx.x = 128-row tile; 4 waves, each wave 32 rows x 128 h.
// For each K-chunk: pack x once, MFMA into all 3 accumulators (q,k,v).
__global__ __launch_bounds__(256, 2) void proj_kernel(
    const float* __restrict__ x,
    const __hip_bfloat16* __restrict__ W3,
    const float2* __restrict__ cs,
    __hip_bfloat16* __restrict__ qbuf,
    __hip_bfloat16* __restrict__ kbuf,
    __hip_bfloat16* __restrict__ vt) {
  const int lane = threadIdx.x & 63;
  const int wid  = threadIdx.x >> 6;
  const int qt   = lane & 15;
  const int g    = lane >> 4;
  const int wrow = blockIdx.x * 128 + wid * 32;

  f32x4 zero = {0.f, 0.f, 0.f, 0.f};
  f32x4 acc[3][2][8];
#pragma unroll
  for (int n = 0; n < 3; ++n)
#pragma unroll
    for (int ti = 0; ti < 2; ++ti)
#pragma unroll
      for (int hi = 0; hi < 8; ++hi) acc[n][ti][hi] = zero;

  const float* xr0 = x + (size_t)(wrow + qt) * CDIM + g * 8;
  const float* xr1 = xr0 + (size_t)16 * CDIM;
  const __hip_bfloat16* wr = W3 + (size_t)qt * CDIM + g * 8;

  for (int c0 = 0; c0 < CDIM; c0 += 32) {
    short8 xa0 = pack_bf16x8(*(const float4*)(xr0 + c0), *(const float4*)(xr0 + c0 + 4));
    short8 xa1 = pack_bf16x8(*(const float4*)(xr1 + c0), *(const float4*)(xr1 + c0 + 4));
#pragma unroll
    for (int n = 0; n < 3; ++n) {
#pragma unroll
      for (int hi = 0; hi < 8; ++hi) {
        short8 wf = *(const short8*)(wr + ((size_t)n * HDIM + hi * 16) * CDIM + c0);
        if (n < 2) {
          acc[n][0][hi] = mfma16(xa0, wf, acc[n][0][hi]);
          acc[n][1][hi] = mfma16(xa1, wf, acc[n][1][hi]);
        } else {
          acc[n][0][hi] = mfma16(wf, xa0, acc[n][0][hi]);
          acc[n][1][hi] = mfma16(wf, xa1, acc[n][1][hi]);
        }
      }
    }
  }

  // epilogue: q/k rope + store; v transposed store
#pragma unroll
  for (int n = 0; n < 2; ++n) {
    __hip_bfloat16* dst = (n == 0) ? qbuf : kbuf;
    const float qmul = (n == 0) ? (QK_SCALE * LOG2E) : 1.0f;
    const float sgn  = (qt & 1) ? 1.0f : -1.0f;
#pragma unroll
    for (int ti = 0; ti < 2; ++ti) {
#pragma unroll
      for (int hi = 0; hi < 8; ++hi) {
        const int h = hi * 16 + qt;
        const int i = h >> 1;
#pragma unroll
        for (int r = 0; r < 4; ++r) {
          const int grow = wrow + ti * 16 + g * 4 + r;
          const int trow = grow & (TSEQ - 1);
          float v   = acc[n][ti][hi][r];
          float prt = __shfl_xor(v, 1);
          float2 c_s = cs[trow * 64 + i];
          float o = (v * c_s.x + prt * c_s.y * sgn) * qmul;
          dst[(size_t)grow * HDIM + h] = __float2bfloat16(o);
        }
      }
    }
  }
#pragma unroll
  for (int ti = 0; ti < 2; ++ti) {
#pragma unroll
    for (int hi = 0; hi < 8; ++hi) {
#pragma unroll
      for (int r = 0; r < 4; ++r) {
        const int h    = hi * 16 + g * 4 + r;
        const int grow = wrow + ti * 16 + qt;
        const int bb   = grow >> 12;
        const int trow = grow & (TSEQ - 1);
        vt[(size_t)bb * (HDIM * TSEQ) + (size_t)h * TSEQ + trow] =
            __float2bfloat16(acc[2][ti][hi][r]);
      }
    }
  }
}

// ---- flash attention step: prefetch next K/V tile, compute current --------
__device__ __forceinline__ void attn_step(
    int tile, int ntiles, int q, int q0w,
    const __hip_bfloat16* kbb, const __hip_bfloat16* vbb,
    int qt, int g, int L0, int L1, int sel,
    const short8 (&qf)[4],
    short8 (&kc)[8], short8 (&vc)[8],     // current tile (consumed)
    short8 (&kn)[8], short8 (&vn)[8],     // next tile (prefetched)
    f32x4 (&acc)[8], float& m, float& lsum) {
  const int kv0 = tile * 32;
  // ---- prefetch next tile into (kn, vn); in flight across QK+softmax ----
  if (tile + 1 < ntiles) {
    const int kv1 = kv0 + 32;
    const __hip_bfloat16* kp = kbb + (size_t)(kv1 + qt) * HDIM + g * 8;
#pragma unroll
    for (int s = 0; s < 4; ++s) {
      kn[s]     = *(const short8*)(kp + s * 32);
      kn[s + 4] = *(const short8*)(kp + 16 * HDIM + s * 32);
    }
    const __hip_bfloat16* vp = vbb + (size_t)qt * TSEQ + kv1 + g * 8;
#pragma unroll
    for (int d = 0; d < 8; ++d)
      vn[d] = *(const short8*)(vp + (size_t)(d * 16) * TSEQ);
  }
  // ---- QK^T (swapped: S^T = K·Q, lane owns one q = lane&15) ----
  f32x4 s0 = {0.f, 0.f, 0.f, 0.f}, s1 = {0.f, 0.f, 0.f, 0.f};
#pragma unroll
  for (int s = 0; s < 4; ++s) {
    s0 = mfma16(kc[s],     qf[s], s0);
    s1 = mfma16(kc[s + 4], qf[s], s1);
  }
  if (kv0 + 31 > q0w) {            // causal mask (tile straddles diagonal)
#pragma unroll
    for (int r = 0; r < 4; ++r) {
      const int kk = kv0 + g * 4 + r;
      if (kk > q)      s0[r] = -1.0e30f;
      if (kk + 16 > q) s1[r] = -1.0e30f;
    }
  }
  float tmax = fmaxf(fmaxf(fmaxf(s0[0], s0[1]), fmaxf(s0[2], s0[3])),
                     fmaxf(fmaxf(s1[0], s1[1]), fmaxf(s1[2], s1[3])));
  tmax = fmaxf(tmax, __shfl_xor(tmax, 16));
  tmax = fmaxf(tmax, __shfl_xor(tmax, 32));
  if (__any(tmax > m + 8.0f)) {    // defer-max (T13)
    const float mn = fmaxf(m, tmax);
    const float f  = exp2f(m - mn);
    lsum *= f;
#pragma unroll
    for (int d = 0; d < 8; ++d) {
      acc[d][0] *= f; acc[d][1] *= f; acc[d][2] *= f; acc[d][3] *= f;
    }
    m = mn;
  }
  float p0[4], p1[4];
#pragma unroll
  for (int r = 0; r < 4; ++r) {
    p0[r] = exp2f(s0[r] - m);      // log2e*scale folded into stored q
    p1[r] = exp2f(s1[r] - m);
    lsum += p0[r] + p1[r];
  }
  // pack P to bf16, permute to B-fragment layout (k = g*8+j per lane)
  const uint32_t pk00 = cvt_pk_bf16(p0[0], p0[1]);
  const uint32_t pk01 = cvt_pk_bf16(p0[2], p0[3]);
  const uint32_t pk10 = cvt_pk_bf16(p1[0], p1[1]);
  const uint32_t pk11 = cvt_pk_bf16(p1[2], p1[3]);
  const int a00 = __shfl((int)pk00, L0), a10 = __shfl((int)pk10, L0);
  const int a01 = __shfl((int)pk01, L0), a11 = __shfl((int)pk11, L0);
  const int a02 = __shfl((int)pk00, L1), a12 = __shfl((int)pk10, L1);
  const int a03 = __shfl((int)pk01, L1), a13 = __shfl((int)pk11, L1);
  union { short8 v; uint32_t u[4]; } pb;
  pb.u[0] = (uint32_t)(sel ? a10 : a00);
  pb.u[1] = (uint32_t)(sel ? a11 : a01);
  pb.u[2] = (uint32_t)(sel ? a12 : a02);
  pb.u[3] = (uint32_t)(sel ? a13 : a03);
  // PV: acc[dt] += V^T-frag · P^T-frag
#pragma unroll
  for (int d = 0; d < 8; ++d)
    acc[d] = mfma16(vc[d], pb.v, acc[d]);
}

// grid (2048): bid&7 = batch (pins each batch's K/V to one XCD's L2),
// bid>>3 = q-chunk, heavy (late-q) chunks first. 1 wave per block.
__global__ __launch_bounds__(64, 2) void attn_kernel(
    const __hip_bfloat16* __restrict__ qbuf,
    const __hip_bfloat16* __restrict__ kbuf,
    const __hip_bfloat16* __restrict__ vt,
    float* __restrict__ out) {
  const int lane = threadIdx.x & 63;
  const int qt   = lane & 15;
  const int g    = lane >> 4;
  const int bid  = blockIdx.x;
  const int b    = bid & 7;
  const int qidx = bid >> 3;
  const int q0w  = (TSEQ / 16 - 1 - qidx) << 4;   // heavy-first
  const int q    = q0w + qt;

  const __hip_bfloat16* qrow = qbuf + (size_t)(b * TSEQ + q) * HDIM + g * 8;
  short8 qf[4];
#pragma unroll
  for (int s = 0; s < 4; ++s) qf[s] = *(const short8*)(qrow + s * 32);

  f32x4 zero = {0.f, 0.f, 0.f, 0.f};
  f32x4 acc[8];
#pragma unroll
  for (int d = 0; d < 8; ++d) acc[d] = zero;
  float m = -3.0e38f, lsum = 0.0f;

  const __hip_bfloat16* kbb = kbuf + (size_t)b * TSEQ * HDIM;
  const __hip_bfloat16* vbb = vt   + (size_t)b * HDIM * TSEQ;
  const int ntiles = (q0w + 47) >> 5;

  const int L0  = qt | ((g & 1) << 5);
  const int L1  = L0 + 16;
  const int sel = g >> 1;

  short8 kA[8], vA[8], kB[8], vB[8];
  { // preload tile 0 into A
    const __hip_bfloat16* kp = kbb + (size_t)qt * HDIM + g * 8;
#pragma unroll
    for (int s = 0; s < 4; ++s) {
      kA[s]     = *(const short8*)(kp + s * 32);
      kA[s + 4] = *(const short8*)(kp + 16 * HDIM + s * 32);
    }
    const __hip_bfloat16* vp = vbb + (size_t)qt * TSEQ + g * 8;
#pragma unroll
    for (int d = 0; d < 8; ++d)
      vB[d] = vA[d] = *(const short8*)(vp + (size_t)(d * 16) * TSEQ);
#pragma unroll
    for (int s = 0; s < 8; ++s) kB[s] = kA[s];
  }

  int t = 0;
  while (true) {
    attn_step(t, ntiles, q, q0w, kbb, vbb, qt, g, L0, L1, sel,
              qf, kA, vA, kB, vB, acc, m, lsum);
    if (++t >= ntiles) break;
    attn_step(t, ntiles, q, q0w, kbb, vbb, qt, g, L0, L1, sel,
              qf, kB, vB, kA, vA, acc, m, lsum);
    if (++t >= ntiles) break;
  }

  lsum += __shfl_xor(lsum, 16);
  lsum += __shfl_xor(lsum, 32);
  const float inv = 1.0f / lsum;
  float* orow = out + (size_t)(b * TSEQ + q) * HDIM;
#pragma unroll
  for (int d = 0; d < 8; ++d) {
    float4 o = make_float4(acc[d][0] * inv, acc[d][1] * inv,
                           acc[d][2] * inv, acc[d][3] * inv);
    *(float4*)(orow + d * 16 + g * 4) = o;
  }
}

// ---- launch ----------------------------------------------------------------
extern "C" void kernel_launch(void* const* d_in, const int* in_sizes, int n_in,
                              void* d_out, int out_size, void* d_ws, size_t ws_size,
                              hipStream_t stream) {
  (void)in_sizes; (void)n_in; (void)out_size; (void)ws_size;
  const float* x  = (const float*)d_in[0];
  const float* Wq = (const float*)d_in[1];
  const float* Wk = (const float*)d_in[2];
  const float* Wv = (const float*)d_in[3];
  float* out = (float*)d_out;

  char* ws = (char*)d_ws;
  float2*         cs   = (float2*)(ws);
  __hip_bfloat16* W3   = (__hip_bfloat16*)(ws + (2u  << 20));
  __hip_bfloat16* qbuf = (__hip_bfloat16*)(ws + (4u  << 20));
  __hip_bfloat16* kbuf = (__hip_bfloat16*)(ws + (12u << 20));
  __hip_bfloat16* vt   = (__hip_bfloat16*)(ws + (20u << 20));

  hipLaunchKernelGGL(prep_kernel, dim3(1536), dim3(256), 0, stream, Wq, Wk, Wv, W3, cs);
  hipLaunchKernelGGL(proj_kernel, dim3(256), dim3(256), 0, stream, x, W3, cs, qbuf, kbuf, vt);
  hipLaunchKernelGGL(attn_kernel, dim3(2048), dim3(64), 0, stream, qbuf, kbuf, vt, out);
}

// Round 3
// 196.339 us; speedup vs baseline: 3.8295x; 2.5747x over previous
//
#include <hip/hip_runtime.h>
#include <hip/hip_bf16.h>
#include <stdint.h>

typedef short short8 __attribute__((ext_vector_type(8)));
typedef float f32x4 __attribute__((ext_vector_type(4)));
typedef __hip_bfloat16 bf16;

#define NBATCH 8
#define TSEQ   4096
#define CDIM   1024
#define HDIM   128
#define QK_SCALE 0.08838834764831845f   // 1/sqrt(128)
#define LOG2E    1.4426950408889634f

// ---- helpers -------------------------------------------------------------
static __device__ __forceinline__ uint32_t cvt_pk_bf16(float lo, float hi) {
  uint32_t r;
  asm("v_cvt_pk_bf16_f32 %0, %1, %2" : "=v"(r) : "v"(lo), "v"(hi));
  return r;
}
static __device__ __forceinline__ short8 pack_bf16x8(float4 a, float4 b) {
  union { short8 v; uint32_t u[4]; } r;
  r.u[0] = cvt_pk_bf16(a.x, a.y);
  r.u[1] = cvt_pk_bf16(a.z, a.w);
  r.u[2] = cvt_pk_bf16(b.x, b.y);
  r.u[3] = cvt_pk_bf16(b.z, b.w);
  return r.v;
}
static __device__ __forceinline__ f32x4 mfma16(short8 a, short8 b, f32x4 c) {
  return __builtin_amdgcn_mfma_f32_16x16x32_bf16(a, b, c, 0, 0, 0);
}
// raw barrier: no vmcnt drain (keep prefetch loads in flight), lgkm drained,
// sched_barrier pins LDS reads below the barrier.
#define BAR() do {                                          \
    asm volatile("s_waitcnt lgkmcnt(0)" ::: "memory");      \
    __builtin_amdgcn_s_barrier();                           \
    __builtin_amdgcn_sched_barrier(0);                      \
  } while (0)

// ---- prep: W -> bf16 cast + rope cos/sin table ----------------------------
__global__ void prep_kernel(const float* __restrict__ Wq,
                            const float* __restrict__ Wk,
                            const float* __restrict__ Wv,
                            bf16* __restrict__ W3,
                            float2* __restrict__ cs) {
  int idx = blockIdx.x * 256 + threadIdx.x;
  if (idx < 3 * HDIM * CDIM) {
    int which = idx >> 17;
    int off   = idx & 131071;
    const float* s = (which == 0) ? Wq : (which == 1) ? Wk : Wv;
    W3[idx] = __float2bfloat16(s[off]);
  }
  if (idx < TSEQ * 64) {
    int t = idx >> 6, i = idx & 63;
    float freq = powf(10000.0f, -(float)i * (1.0f / 64.0f));
    float ang  = (float)t * freq;
    cs[idx] = make_float2(cosf(ang), sinf(ang));
  }
}

// ---- projection: LDS-staged x (bf16, swizzled, dbuf), W from L2 ------------
// grid 512, block 512 (8 waves). Block = 64 rows x 384 cols (24 col-frags,
// 3 per wave). K-loop: 16 steps of BK=64, one raw barrier per step.
__global__ __launch_bounds__(512) void proj_kernel(
    const float* __restrict__ x, const bf16* __restrict__ W3,
    const float2* __restrict__ cs, bf16* __restrict__ qbuf,
    bf16* __restrict__ kbuf, bf16* __restrict__ vt) {
  __shared__ __align__(16) char xlds[2][8192];
  const int tid = threadIdx.x, lane = tid & 63, wid = tid >> 6;
  const int qt = lane & 15, g = lane >> 4;
  const int row0 = blockIdx.x * 64;
  const int swz = (qt & 7) << 4;

  // staging: thread -> (row, 8-elem k chunk); write swizzled bf16x8
  const int srow = tid >> 3;
  const int sbyte = srow * 128 + (((tid & 7) * 16) ^ ((srow & 7) << 4));
  const float* xsrc = x + (size_t)(row0 + srow) * CDIM + (tid & 7) * 8;

  const int cf0 = wid * 3;   // col-frags cf0..cf0+2 ; cf<16 -> q/k, else v
  const bf16* wr0 = W3 + (size_t)(cf0 * 16 + qt) * CDIM + g * 8;
  const bf16* wr1 = wr0 + (size_t)16 * CDIM;
  const bf16* wr2 = wr0 + (size_t)32 * CDIM;

  f32x4 acc[3][4];
#pragma unroll
  for (int j = 0; j < 3; ++j)
#pragma unroll
    for (int ti = 0; ti < 4; ++ti) acc[j][ti] = (f32x4){0.f, 0.f, 0.f, 0.f};

  // prologue: stage step 0
  float4 a0 = *(const float4*)(xsrc), a1 = *(const float4*)(xsrc + 4);
  *(short8*)(&xlds[0][sbyte]) = pack_bf16x8(a0, a1);
  BAR();

  for (int s = 0; s < 16; ++s) {
    const bool hn = (s < 15);
    if (hn) {   // async-split: issue next loads before compute
      a0 = *(const float4*)(xsrc + (s + 1) * 64);
      a1 = *(const float4*)(xsrc + (s + 1) * 64 + 4);
    }
    const char* xb = xlds[s & 1];
#pragma unroll
    for (int ks = 0; ks < 2; ++ks) {
      short8 xa[4];
#pragma unroll
      for (int ti = 0; ti < 4; ++ti)
        xa[ti] = *(const short8*)(xb + (ti * 16 + qt) * 128 + ((ks * 64 + g * 16) ^ swz));
      const int ko = s * 64 + ks * 32;
      short8 w0 = *(const short8*)(wr0 + ko);
      short8 w1 = *(const short8*)(wr1 + ko);
      short8 w2 = *(const short8*)(wr2 + ko);
#pragma unroll
      for (int ti = 0; ti < 4; ++ti) {
        acc[0][ti] = (cf0 + 0 < 16) ? mfma16(xa[ti], w0, acc[0][ti]) : mfma16(w0, xa[ti], acc[0][ti]);
        acc[1][ti] = (cf0 + 1 < 16) ? mfma16(xa[ti], w1, acc[1][ti]) : mfma16(w1, xa[ti], acc[1][ti]);
        acc[2][ti] = (cf0 + 2 < 16) ? mfma16(xa[ti], w2, acc[2][ti]) : mfma16(w2, xa[ti], acc[2][ti]);
      }
    }
    if (hn) *(short8*)(&xlds[(s + 1) & 1][sbyte]) = pack_bf16x8(a0, a1);
    BAR();
  }

  // epilogue
#pragma unroll
  for (int j = 0; j < 3; ++j) {
    const int cf = cf0 + j;
    if (cf < 16) {   // q (n=0) / k (n=1): D[t][h], rope, store
      const int n = cf >> 3;
      const int h = (cf & 7) * 16 + qt;
      bf16* dst = n ? kbuf : qbuf;
      const float qmul = n ? 1.0f : (QK_SCALE * LOG2E);
      const float sgn = (h & 1) ? 1.0f : -1.0f;
#pragma unroll
      for (int ti = 0; ti < 4; ++ti)
#pragma unroll
        for (int rr = 0; rr < 4; ++rr) {
          const int grow = row0 + ti * 16 + g * 4 + rr;
          const int trow = grow & (TSEQ - 1);
          const float v = acc[j][ti][rr];
          const float prt = __shfl_xor(v, 1);
          const float2 c_s = cs[trow * 64 + (h >> 1)];
          dst[(size_t)grow * HDIM + h] =
              __float2bfloat16((v * c_s.x + prt * c_s.y * sgn) * qmul);
        }
    } else {         // v: D[h][t] (swapped operands) -> direct v^T store
#pragma unroll
      for (int ti = 0; ti < 4; ++ti)
#pragma unroll
        for (int rr = 0; rr < 4; ++rr) {
          const int h = (cf & 7) * 16 + g * 4 + rr;
          const int grow = row0 + ti * 16 + qt;
          vt[(size_t)(grow >> 12) * (HDIM * TSEQ) + (size_t)h * TSEQ + (grow & (TSEQ - 1))] =
              __float2bfloat16(acc[j][ti][rr]);
        }
    }
  }
}

// ---- attention: split-kv flash, LDS-staged K/V tiles -----------------------
// grid 512 x 256thr (4 waves). block = (batch=bid&7, item=bid>>3).
// item -> chunk c = 31-(item>>1) (heavy first), half = item&1.
// chunk c: q in [c*128,(c+1)*128); kv-half of [0,(c+1)*128), 64-multiples.
// wave = 32 q (2 q-frags). K tile [64][128] + V^T tile [128][64] in LDS,
// XOR-swizzled, double-buffered (reg-staged, one raw barrier per tile).
struct Stage { short8 v[8]; };

static __device__ __forceinline__ void stage_load(Stage& s, const bf16* kbb,
                                                  const bf16* vbb, int kv0,
                                                  int wid, int lane) {
  const int g = lane >> 4, qt = lane & 15;
#pragma unroll
  for (int i = 0; i < 4; ++i) {
    const int row = wid * 16 + i * 4 + g;
    s.v[i] = *(const short8*)(kbb + (size_t)(kv0 + row) * HDIM + qt * 8);
  }
#pragma unroll
  for (int i = 0; i < 4; ++i) {
    const int row = wid * 32 + i * 8 + (lane >> 3);
    s.v[4 + i] = *(const short8*)(vbb + (size_t)row * TSEQ + kv0 + (lane & 7) * 8);
  }
}
static __device__ __forceinline__ void stage_write(const Stage& s, char* buf,
                                                   int wid, int lane) {
  const int g = lane >> 4, qt = lane & 15;
#pragma unroll
  for (int i = 0; i < 4; ++i) {
    const int row = wid * 16 + i * 4 + g;
    *(short8*)(buf + row * 256 + ((qt * 16) ^ ((row & 7) << 4))) = s.v[i];
  }
#pragma unroll
  for (int i = 0; i < 4; ++i) {
    const int row = wid * 32 + i * 8 + (lane >> 3);
    *(short8*)(buf + 16384 + row * 128 + (((lane & 7) * 16) ^ ((row & 7) << 4))) = s.v[4 + i];
  }
}

__global__ __launch_bounds__(256) void attn_kernel(
    const bf16* __restrict__ qbuf, const bf16* __restrict__ kbuf,
    const bf16* __restrict__ vt, float* __restrict__ outp,
    bf16* __restrict__ part1, float2* __restrict__ ml) {
  __shared__ __align__(16) char lds[2][32768];
  const int tid = threadIdx.x, lane = tid & 63, wid = tid >> 6;
  const int qt = lane & 15, g = lane >> 4;
  const int bid = blockIdx.x;
  const int b = bid & 7;                 // batch -> XCD pin
  const int it = bid >> 3;               // 0..63, heavy first
  const int c = 31 - (it >> 1);
  const int half = it & 1;
  const int Shalf = (c + 1) * 64;        // kv half-size (64-multiple)
  const int kvbeg = half * Shalf;
  const int nt = c + 1;                  // tiles of 64 in this half
  const int q0 = c * 128;
  const int qminw = q0 + wid * 32;
  const int swz = (qt & 7) << 4;
  const int L0 = qt | ((g & 1) << 5);
  const int L1 = L0 + 16;
  const int sel = g >> 1;

  const bf16* kbb = kbuf + (size_t)b * TSEQ * HDIM;
  const bf16* vbb = vt + (size_t)b * HDIM * TSEQ;

  short8 qf8[2][4];
#pragma unroll
  for (int qf = 0; qf < 2; ++qf)
#pragma unroll
    for (int ks = 0; ks < 4; ++ks)
      qf8[qf][ks] = *(const short8*)(qbuf +
          (size_t)(b * TSEQ + qminw + qf * 16 + qt) * HDIM + ks * 32 + g * 8);

  f32x4 acc[8][2];
#pragma unroll
  for (int dt = 0; dt < 8; ++dt)
#pragma unroll
    for (int qf = 0; qf < 2; ++qf) acc[dt][qf] = (f32x4){0.f, 0.f, 0.f, 0.f};
  float m[2] = {-3.0e38f, -3.0e38f}, l[2] = {0.f, 0.f};

  Stage st;
  stage_load(st, kbb, vbb, kvbeg, wid, lane);
  stage_write(st, lds[0], wid, lane);
  BAR();

  for (int t = 0; t < nt; ++t) {
    const int kv0 = kvbeg + t * 64;
    const bool hn = (t + 1 < nt);
    if (hn) stage_load(st, kbb, vbb, kv0 + 64, wid, lane);   // in flight over compute

    if (kv0 <= qminw + 31) {             // skip fully-masked tiles (still stage+barrier)
      const char* Kl = lds[t & 1];
      const char* Vl = Kl + 16384;
      // ---- QK^T (swapped: lane owns q = qf*16+qt; kv = kv0+kt*16+g*4+rr)
      f32x4 sc[2][4];
#pragma unroll
      for (int qf = 0; qf < 2; ++qf)
#pragma unroll
        for (int kt = 0; kt < 4; ++kt) sc[qf][kt] = (f32x4){0.f, 0.f, 0.f, 0.f};
#pragma unroll
      for (int kt = 0; kt < 4; ++kt) {
        short8 kf[4];
#pragma unroll
        for (int ks = 0; ks < 4; ++ks)
          kf[ks] = *(const short8*)(Kl + (kt * 16 + qt) * 256 + ((ks * 64 + g * 16) ^ swz));
#pragma unroll
        for (int ks = 0; ks < 4; ++ks) {
          sc[0][kt] = mfma16(kf[ks], qf8[0][ks], sc[0][kt]);
          sc[1][kt] = mfma16(kf[ks], qf8[1][ks], sc[1][kt]);
        }
      }
      // ---- causal mask
      if (kv0 + 63 > qminw) {
#pragma unroll
        for (int qf = 0; qf < 2; ++qf) {
          const int q = qminw + qf * 16 + qt;
#pragma unroll
          for (int kt = 0; kt < 4; ++kt)
#pragma unroll
            for (int rr = 0; rr < 4; ++rr)
              if (kv0 + kt * 16 + g * 4 + rr > q) sc[qf][kt][rr] = -1.0e30f;
        }
      }
      // ---- online softmax (exp2 domain; scale*log2e folded into q)
      short8 pbv[2][2];
#pragma unroll
      for (int qf = 0; qf < 2; ++qf) {
        float tmax = -3.0e38f;
#pragma unroll
        for (int kt = 0; kt < 4; ++kt)
#pragma unroll
          for (int rr = 0; rr < 4; ++rr) tmax = fmaxf(tmax, sc[qf][kt][rr]);
        tmax = fmaxf(tmax, __shfl_xor(tmax, 16));
        tmax = fmaxf(tmax, __shfl_xor(tmax, 32));
        if (__any(tmax > m[qf] + 8.0f)) {   // defer-max (T13)
          const float mn = fmaxf(m[qf], tmax);
          const float f = exp2f(m[qf] - mn);
          l[qf] *= f;
#pragma unroll
          for (int dt = 0; dt < 8; ++dt) {
            acc[dt][qf][0] *= f; acc[dt][qf][1] *= f;
            acc[dt][qf][2] *= f; acc[dt][qf][3] *= f;
          }
          m[qf] = mn;
        }
        float psum = 0.f;
#pragma unroll
        for (int kt = 0; kt < 4; ++kt)
#pragma unroll
          for (int rr = 0; rr < 4; ++rr) {
            const float p = exp2f(sc[qf][kt][rr] - m[qf]);
            sc[qf][kt][rr] = p; psum += p;
          }
        l[qf] += psum;
        // pack P -> bf16 B-frags (k = g*8+j), two 32-kv chunks
#pragma unroll
        for (int kch = 0; kch < 2; ++kch) {
          const f32x4 p0 = sc[qf][kch * 2], p1 = sc[qf][kch * 2 + 1];
          const uint32_t pk00 = cvt_pk_bf16(p0[0], p0[1]);
          const uint32_t pk01 = cvt_pk_bf16(p0[2], p0[3]);
          const uint32_t pk10 = cvt_pk_bf16(p1[0], p1[1]);
          const uint32_t pk11 = cvt_pk_bf16(p1[2], p1[3]);
          const int a00 = __shfl((int)pk00, L0), a10 = __shfl((int)pk10, L0);
          const int a01 = __shfl((int)pk01, L0), a11 = __shfl((int)pk11, L0);
          const int a02 = __shfl((int)pk00, L1), a12 = __shfl((int)pk10, L1);
          const int a03 = __shfl((int)pk01, L1), a13 = __shfl((int)pk11, L1);
          union { short8 v; uint32_t u[4]; } pbu;
          pbu.u[0] = (uint32_t)(sel ? a10 : a00);
          pbu.u[1] = (uint32_t)(sel ? a11 : a01);
          pbu.u[2] = (uint32_t)(sel ? a12 : a02);
          pbu.u[3] = (uint32_t)(sel ? a13 : a03);
          pbv[qf][kch] = pbu.v;
        }
      }
      // ---- PV: acc[dt] += V^T-frag x P-frag
#pragma unroll
      for (int dt = 0; dt < 8; ++dt) {
        const short8 vf0 = *(const short8*)(Vl + (dt * 16 + qt) * 128 + ((g * 16) ^ swz));
        const short8 vf1 = *(const short8*)(Vl + (dt * 16 + qt) * 128 + ((64 + g * 16) ^ swz));
        acc[dt][0] = mfma16(vf0, pbv[0][0], acc[dt][0]);
        acc[dt][1] = mfma16(vf0, pbv[1][0], acc[dt][1]);
        acc[dt][0] = mfma16(vf1, pbv[0][1], acc[dt][0]);
        acc[dt][1] = mfma16(vf1, pbv[1][1], acc[dt][1]);
      }
    }

    if (hn) stage_write(st, lds[(t + 1) & 1], wid, lane);
    BAR();
  }

  // ---- store normalized partial + (m,l)
#pragma unroll
  for (int qf = 0; qf < 2; ++qf) {
    float ls = l[qf];
    ls += __shfl_xor(ls, 16);
    ls += __shfl_xor(ls, 32);
    const float inv = ls > 0.f ? 1.0f / ls : 0.f;
    const int qg = b * TSEQ + qminw + qf * 16 + qt;
    if (half == 0) {
      float* orow = outp + (size_t)qg * HDIM;
#pragma unroll
      for (int dt = 0; dt < 8; ++dt) {
        *(float2*)(orow + dt * 16 + g * 4) =
            make_float2(acc[dt][qf][0] * inv, acc[dt][qf][1] * inv);
        *(float2*)(orow + dt * 16 + g * 4 + 2) =
            make_float2(acc[dt][qf][2] * inv, acc[dt][qf][3] * inv);
      }
    } else {
      bf16* prow = part1 + (size_t)qg * HDIM;
#pragma unroll
      for (int dt = 0; dt < 8; ++dt) {
        *(uint32_t*)(prow + dt * 16 + g * 4) =
            cvt_pk_bf16(acc[dt][qf][0] * inv, acc[dt][qf][1] * inv);
        *(uint32_t*)(prow + dt * 16 + g * 4 + 2) =
            cvt_pk_bf16(acc[dt][qf][2] * inv, acc[dt][qf][3] * inv);
      }
    }
    if (g == 0) ml[half * (NBATCH * TSEQ) + qg] = make_float2(m[qf], ls);
  }
}

// ---- combine the two kv-halves ---------------------------------------------
__global__ __launch_bounds__(256) void combine_kernel(
    float* __restrict__ outp, const bf16* __restrict__ part1,
    const float2* __restrict__ ml) {
  const int gid = blockIdx.x * 256 + threadIdx.x;   // 131072
  const int qg = gid >> 2, dch = (gid & 3) * 32;
  const float2 ml0 = ml[qg], ml1 = ml[NBATCH * TSEQ + qg];
  const float mm = fmaxf(ml0.x, ml1.x);
  const float w0 = exp2f(ml0.x - mm) * ml0.y;
  const float w1 = exp2f(ml1.x - mm) * ml1.y;
  const float inv = 1.0f / (w0 + w1);
  float* o = outp + (size_t)qg * HDIM + dch;
  const bf16* p1 = part1 + (size_t)qg * HDIM + dch;
#pragma unroll
  for (int j = 0; j < 32; j += 8) {
    float4 a0 = *(const float4*)(o + j);
    float4 a1 = *(const float4*)(o + j + 4);
    short8 pv = *(const short8*)(p1 + j);
    float r[8];
#pragma unroll
    for (int e = 0; e < 8; ++e) {
      union { uint32_t u; float f; } cv;
      cv.u = ((uint32_t)(uint16_t)pv[e]) << 16;
      const float a = (e < 4) ? (&a0.x)[e] : (&a1.x)[e - 4];
      r[e] = (w0 * a + w1 * cv.f) * inv;
    }
    *(float4*)(o + j) = make_float4(r[0], r[1], r[2], r[3]);
    *(float4*)(o + j + 4) = make_float4(r[4], r[5], r[6], r[7]);
  }
}

// ---- launch ----------------------------------------------------------------
extern "C" void kernel_launch(void* const* d_in, const int* in_sizes, int n_in,
                              void* d_out, int out_size, void* d_ws, size_t ws_size,
                              hipStream_t stream) {
  (void)in_sizes; (void)n_in; (void)out_size; (void)ws_size;
  const float* x  = (const float*)d_in[0];
  const float* Wq = (const float*)d_in[1];
  const float* Wk = (const float*)d_in[2];
  const float* Wv = (const float*)d_in[3];
  float* out = (float*)d_out;

  // ws: [0,2M) cs | [2M,4M) W3 | [4M,12M) q | [12M,20M) k | [20M,28M) v^T
  //     [28M,36M) part1 (bf16 O of kv-half1) | [36M,+512K) ml float2[2][32768]
  char* ws = (char*)d_ws;
  float2* cs   = (float2*)(ws);
  bf16*   W3   = (bf16*)(ws + (2u  << 20));
  bf16*   qbuf = (bf16*)(ws + (4u  << 20));
  bf16*   kbuf = (bf16*)(ws + (12u << 20));
  bf16*   vt   = (bf16*)(ws + (20u << 20));
  bf16*   p1   = (bf16*)(ws + (28u << 20));
  float2* ml   = (float2*)(ws + (36u << 20));

  hipLaunchKernelGGL(prep_kernel, dim3(1536), dim3(256), 0, stream, Wq, Wk, Wv, W3, cs);
  hipLaunchKernelGGL(proj_kernel, dim3(512), dim3(512), 0, stream, x, W3, cs, qbuf, kbuf, vt);
  hipLaunchKernelGGL(attn_kernel, dim3(512), dim3(256), 0, stream, qbuf, kbuf, vt, out, p1, ml);
  hipLaunchKernelGGL(combine_kernel, dim3(512), dim3(256), 0, stream, out, p1, ml);
}